// Round 11
// baseline (77.641 us; speedup 1.0000x reference)
//
#include <hip/hip_runtime.h>
#include <hip/hip_bf16.h>
#include <math.h>
#include <stddef.h>

// Problem constants (from reference)
#define NB 8
#define NT 1024
#define NF 80
#define NSTACK 4
#define NSTRIDE 4
#define NG 4
#define NE 16
#define NC 8192
#define ND 512
#define NTS 256          // (NT-NSTACK)/NSTRIDE + 1
#define NP (NB*NTS)      // 2048 subsampled positions
#define SFD (NSTACK*NF)  // 320
#define FREG 0.01f
#define LNEPS 1e-5f

// fp32-fallback k_logits tiling
#define TCC 1024
#define CPT 4
#define PCH 16
#define PB 16

// MFMA path
#define ROWS_MAX 2176     // >= ceil(2048/144)*144 = 2160
#define ROWCH 144         // rows per chunk (all in acc regs)
#define MT 9              // 16-row m-tiles per chunk
#define QCH 16            // lat rows staged per k_qdist pass (4 KB LDS)
#define QY 16             // k_qdist row-split factor (grid.y)
#define CT 128            // c-tiles of 64 for the logits GEMM partials
#define QS 8              // qdist atomic spread slots
#define STG16H 1152       // 16B chunks per HALF stage (2 kh x 4 hi4 x 144 rows)

typedef __attribute__((ext_vector_type(8))) short short8;
typedef __attribute__((ext_vector_type(4))) float f32x4;

struct Ws {
  // header: zeroed by k_zero (big path) / memset (fallback)
  float penSum;
  unsigned int nA;
  unsigned int maskIsInt;
  unsigned int pad1;
  unsigned long long amax[NP*NG];   // plain-stored by k_red_l (big) / atomics (fallback)
  float sumExp[NP*NG];
  float tLogit[NP*NG];
  int   targets[NP*NG];
  int   activeList[NP];
  unsigned int bitmap[NC/32];       // unused (kept for layout stability)
  // initialized by k_prologue (big path)
  unsigned long long aminS[NP*NG*QS]; // qdist spread argmin slots (0xFF)
  // no init needed
  float lat[NP][64];
  // fragment-order bf16 splits: aHiT[((k/8)*ROWS_MAX + row)*8 + (k%8)]
  unsigned short aHiT[(size_t)(ND/8)*ROWS_MAX*8];
  unsigned short aLoT[(size_t)(ND/8)*ROWS_MAX*8];
  float part_se[NG][ROWS_MAX][CT];
  unsigned long long part_mx[NG][ROWS_MAX][CT];
};

__device__ inline unsigned short bf16_rne(float x) {
  unsigned u = __float_as_uint(x);
  unsigned r = u + 0x7FFFu + ((u >> 16) & 1u);
  return (unsigned short)(r >> 16);
}
__device__ inline unsigned fkey_asc(float d) {  // ascending float -> ascending uint
  unsigned u = __float_as_uint(d);
  return (u & 0x80000000u) ? ~u : (u | 0x80000000u);
}
__device__ __forceinline__ void gload_lds16(const void* g, void* l) {
  __builtin_amdgcn_global_load_lds(
      (const __attribute__((address_space(1))) void*)g,
      (__attribute__((address_space(3))) void*)l, 16, 0, 0);
}

// ---- tiny header zero (replaces 169 KB memset in the big path) ----
__global__ void k_zero(Ws* ws) {
  if (threadIdx.x == 0) {
    ws->penSum = 0.f;
    ws->nA = 0u;
    ws->maskIsInt = 0u;
    ws->pad1 = 0u;
  }
}

// ---- fused prologue: features_pen + mask/compact + aminS init ----
__global__ __launch_bounds__(256) void k_prologue(
    const float* __restrict__ feats, const float* __restrict__ mean,
    const float* __restrict__ istd, const unsigned char* __restrict__ m8,
    const int* __restrict__ lens, int doClear, Ws* ws) {
  const int tid = threadIdx.x;
  if (doClear) ws->aminS[(size_t)blockIdx.x*256 + tid] = ~0ull;

  const int N4 = NB*NT*NF/4;
  float s = 0.f;
  for (int i = blockIdx.x*256 + tid; i < N4; i += gridDim.x*256) {
    float4 v = reinterpret_cast<const float4*>(feats)[i];
    int f0 = (i*4) % NF;
    float x0 = (v.x - mean[f0+0]) * istd[f0+0];
    float x1 = (v.y - mean[f0+1]) * istd[f0+1];
    float x2 = (v.z - mean[f0+2]) * istd[f0+2];
    float x3 = (v.w - mean[f0+3]) * istd[f0+3];
    s += x0*x0 + x1*x1 + x2*x2 + x3*x3;
  }
  for (int o = 32; o; o >>= 1) s += __shfl_down(s, o);
  __shared__ float pr[4];
  if ((tid & 63) == 0) pr[tid >> 6] = s;
  __syncthreads();
  if (tid == 0) atomicAdd(&ws->penSum, pr[0]+pr[1]+pr[2]+pr[3]);

  if (blockIdx.x < NP/256) {
    __shared__ unsigned flag;
    if (tid == 0) flag = 0;
    __syncthreads();
    unsigned nz = 0;
    int base = tid * 32;
    for (int i = base; i < base + 32; ++i)
      if ((i & 3) && m8[i]) nz = 1;
    if (nz) atomicOr(&flag, 1u);
    __syncthreads();
    bool isInt = (flag == 0);

    int p = blockIdx.x*256 + tid;
    int b = p >> 8, ts = p & (NTS-1);
    int t0 = b*NT + ts*NSTRIDE;
    bool allm;
    if (isInt) {
      const int* m32 = (const int*)m8;
      allm = m32[t0] && m32[t0+1] && m32[t0+2] && m32[t0+3];
    } else {
      allm = m8[t0] && m8[t0+1] && m8[t0+2] && m8[t0+3];
    }
    int ls = (lens[b] - NSTACK)/NSTRIDE + 1;
    if (ls < 0) ls = 0;
    if (allm && ts < ls) {
      unsigned idx = atomicAdd(&ws->nA, 1u);
      ws->activeList[idx] = p;
    }
  }
}

// ---- fused: latents (stack+LN+proj) AND fragment-order enc bf16 split ----
__global__ __launch_bounds__(256) void k_latprep(
    const float* __restrict__ feats, const float* __restrict__ mean,
    const float* __restrict__ istd, const float* __restrict__ projw,
    const float* __restrict__ enc, Ws* ws) {
  int nA = (int)ws->nA;
  int ai = blockIdx.x;
  int limit = ((nA + ROWCH - 1) / ROWCH) * ROWCH;
  int tid = threadIdx.x;

  if (ai >= nA) {
    if (ai < limit && tid < 64) {     // zero-pad fragment rows
      short8 z;
      #pragma unroll
      for (int j = 0; j < 8; ++j) z[j] = 0;
      *reinterpret_cast<short8*>(ws->aHiT + ((size_t)tid*ROWS_MAX + ai)*8) = z;
      *reinterpret_cast<short8*>(ws->aLoT + ((size_t)tid*ROWS_MAX + ai)*8) = z;
    }
    return;
  }

  int p = ws->activeList[ai];
  if (tid < 64) {
    const float* src = enc + (size_t)p*ND + tid*8;
    float4 x0 = *reinterpret_cast<const float4*>(src);
    float4 x1 = *reinterpret_cast<const float4*>(src + 4);
    float xv[8] = {x0.x, x0.y, x0.z, x0.w, x1.x, x1.y, x1.z, x1.w};
    short8 h, l;
    #pragma unroll
    for (int j = 0; j < 8; ++j) {
      unsigned short hi = bf16_rne(xv[j]);
      float rem = xv[j] - __uint_as_float((unsigned)hi << 16);
      h[j] = (short)hi;
      l[j] = (short)bf16_rne(rem);
    }
    *reinterpret_cast<short8*>(ws->aHiT + ((size_t)tid*ROWS_MAX + ai)*8) = h;
    *reinterpret_cast<short8*>(ws->aLoT + ((size_t)tid*ROWS_MAX + ai)*8) = l;
  }

  int b = p >> 8, ts = p & (NTS-1);
  __shared__ float sN[SFD];
  __shared__ float sPart[4*64];
  __shared__ float rS[4], rQ[4];

  for (int j = tid; j < SFD; j += 256) {
    int k = j / NF, f = j - k*NF;
    sN[j] = (feats[((size_t)b*NT + ts*NSTRIDE + k)*NF + f] - mean[f]) * istd[f];
  }
  __syncthreads();
  float s = 0.f, q = 0.f;
  for (int j = tid; j < SFD; j += 256) { float x = sN[j]; s += x; q += x*x; }
  for (int o = 32; o; o >>= 1) { s += __shfl_down(s, o); q += __shfl_down(q, o); }
  if ((tid & 63) == 0) { rS[tid>>6] = s; rQ[tid>>6] = q; }
  __syncthreads();
  float mu  = (rS[0]+rS[1]+rS[2]+rS[3]) * (1.f/SFD);
  float var = (rQ[0]+rQ[1]+rQ[2]+rQ[3]) * (1.f/SFD) - mu*mu;
  float inv = rsqrtf(var + LNEPS);
  for (int j = tid; j < SFD; j += 256) sN[j] = (sN[j]-mu)*inv;
  __syncthreads();
  {
    int j = tid & 63, part = tid >> 6;
    float a = 0.f;
    int i0 = part*80;
    for (int i = i0; i < i0+80; ++i) a = fmaf(sN[i], projw[i*64 + j], a);
    sPart[part*64 + j] = a;
  }
  __syncthreads();
  if (tid < 64)
    ws->lat[ai][tid] = sPart[tid] + sPart[64+tid] + sPart[128+tid] + sPart[192+tid];
}

// ---- codebook argmin, c-parallel, 16-way row-split; spread atomicMin ----
__global__ __launch_bounds__(256) void k_qdist(const float* __restrict__ emb, Ws* ws) {
  int nA = (int)ws->nA;
  if (nA == 0) return;
  int tid = threadIdx.x;
  int g = tid >> 6, lane = tid & 63;
  int c = blockIdx.x * 64 + lane;
  int per = (nA + QY - 1) / QY;
  int a0 = blockIdx.y * per;
  int a1 = min(nA, a0 + per);
  int slot = blockIdx.x & (QS-1);

  const float4* e4 = reinterpret_cast<const float4*>(emb + ((size_t)c*NG + g)*NE);
  float4 b0 = e4[0], b1 = e4[1], b2 = e4[2], b3 = e4[3];
  float n2 = b0.x*b0.x + b0.y*b0.y + b0.z*b0.z + b0.w*b0.w
           + b1.x*b1.x + b1.y*b1.y + b1.z*b1.z + b1.w*b1.w
           + b2.x*b2.x + b2.y*b2.y + b2.z*b2.z + b2.w*b2.w
           + b3.x*b3.x + b3.y*b3.y + b3.z*b3.z + b3.w*b3.w;

  __shared__ float sL[QCH][64];
  for (int base = a0; base < a1; base += QCH) {
    int cnt = min(QCH, a1 - base);
    __syncthreads();
    for (int i = tid; i < cnt*64; i += 256)
      (&sL[0][0])[i] = (&ws->lat[0][0])[(size_t)(base + (i >> 6))*64 + (i & 63)];
    __syncthreads();
    for (int i = 0; i < cnt; ++i) {
      const float* lp = &sL[i][g*NE];
      float dot = lp[0]*b0.x + lp[1]*b0.y + lp[2]*b0.z + lp[3]*b0.w
                + lp[4]*b1.x + lp[5]*b1.y + lp[6]*b1.z + lp[7]*b1.w
                + lp[8]*b2.x + lp[9]*b2.y + lp[10]*b2.z + lp[11]*b2.w
                + lp[12]*b3.x + lp[13]*b3.y + lp[14]*b3.z + lp[15]*b3.w;
      float d = n2 - 2.f*dot;
      float mv = d; int mc = c;
      #pragma unroll
      for (int off = 32; off; off >>= 1) {
        float ov = __shfl_xor(mv, off);
        int   oc = __shfl_xor(mc, off);
        if (ov < mv || (ov == mv && oc < mc)) { mv = ov; mc = oc; }
      }
      if (lane == 0) {
        unsigned long long key =
            ((unsigned long long)fkey_asc(mv) << 32) | (unsigned)mc;
        atomicMin(&ws->aminS[(size_t)((base + i)*NG + g)*QS + slot], key);
      }
    }
  }
}

// ---- logits GEMM: W read+split once (A-operand), enc fragment-order
// (B-operand) staged per k-step into split H/L LDS buffers (pipelined:
// issue L(s) -> consume H(s) -> barrier -> issue H(s+1) -> consume L(s)),
// in-block K-split across waves, target extraction fused into epilogue ----
__global__ __launch_bounds__(512, 4) void k_logits_mfma(
    const float* __restrict__ W, const float* __restrict__ bias, Ws* ws) {
  const int nA = (int)ws->nA;
  if (nA == 0) return;
  const int nCh = (nA + ROWCH - 1) / ROWCH;
  const int tid = threadIdx.x;
  const int wave = tid >> 6, lane = tid & 63;
  const int sub = wave & 3, kh = wave >> 2;
  const int g = blockIdx.y;
  const int c0w = blockIdx.x * 64 + sub * 16;
  const int lo16 = lane & 15, hi4 = lane >> 4;
  const int cA = c0w + lo16;           // A-fragment column
  const int cOut0 = c0w + hi4*4;       // this lane's 4 output c's
  float bv[4];
  #pragma unroll
  for (int v = 0; v < 4; ++v) bv[v] = bias[g*NC + cOut0 + v];

  // Union region: k-loop -> H (18432) + L (18432) stage buffers;
  // epilogue -> sAcc (36864) + sEs (2304 pad 2560) + sMx (4608).
  __shared__ __align__(16) unsigned char smem[45056];
  unsigned short* sH = (unsigned short*)smem;
  unsigned short* sLb = (unsigned short*)(smem + 18432);
  f32x4 (*sAcc)[MT][64] = (f32x4 (*)[MT][64])smem;
  float (*sEs)[ROWCH] = (float (*)[ROWCH])(smem + 36864);
  unsigned long long (*sMx)[ROWCH] =
      (unsigned long long (*)[ROWCH])(smem + 36864 + 2560);

  // W base for this wave's k-half: k = kh*256 + step*32 + hi4*8
  const float* __restrict__ wBase =
      W + (((size_t)g*ND + (size_t)kh*256 + hi4*8)*NC) + cA;

  for (int ch = 0; ch < nCh; ++ch) {
    const int r0 = ch * ROWCH;

    // per-thread half-stage source offsets (shorts): t -> (khh,h4,row)
    size_t off0, off1, off2; bool v2;
    {
      int t = tid;                         // < 512
      int part = t/144, row = t - part*144;
      off0 = ((size_t)((part>>2)*32 + (part&3))*ROWS_MAX + r0 + row)*8;
      t = tid + 512;                       // < 1024
      part = t/144; row = t - part*144;
      off1 = ((size_t)((part>>2)*32 + (part&3))*ROWS_MAX + r0 + row)*8;
      t = tid + 1024;
      v2 = (t < STG16H);
      part = t/144; row = t - part*144;
      off2 = v2 ? ((size_t)((part>>2)*32 + (part&3))*ROWS_MAX + r0 + row)*8 : 0;
    }

    f32x4 acc[MT];
    #pragma unroll
    for (int mt = 0; mt < MT; ++mt) acc[mt] = (f32x4){0.f, 0.f, 0.f, 0.f};

    // stage bh(0) -> H
    gload_lds16(ws->aHiT + off0, sH + (size_t)tid*8);
    gload_lds16(ws->aHiT + off1, sH + (size_t)(tid + 512)*8);
    if (v2) gload_lds16(ws->aHiT + off2, sH + (size_t)(tid + 1024)*8);
    __syncthreads();

    #pragma unroll 1
    for (int step = 0; step < 8; ++step) {
      const size_t kAdv = (size_t)step*4*ROWS_MAX*8;
      // stage bl(step) -> L (async, hides under consume-H)
      gload_lds16(ws->aLoT + off0 + kAdv, sLb + (size_t)tid*8);
      gload_lds16(ws->aLoT + off1 + kAdv, sLb + (size_t)(tid + 512)*8);
      if (v2) gload_lds16(ws->aLoT + off2 + kAdv, sLb + (size_t)(tid + 1024)*8);
      // W loads + convert
      float wv[8];
      {
        const float* wp = wBase + (size_t)step*32*NC;
        #pragma unroll
        for (int j = 0; j < 8; ++j) wv[j] = wp[(size_t)j*NC];
      }
      short8 whi, wlo;
      #pragma unroll
      for (int j = 0; j < 8; ++j) {
        unsigned short h = bf16_rne(wv[j]);
        float rem = wv[j] - __uint_as_float((unsigned)h << 16);
        whi[j] = (short)h;
        wlo[j] = (short)bf16_rne(rem);
      }
      // consume H: hi-operand products (whi*bh, wlo*bh)
      const unsigned short* bpH = sH + ((size_t)((kh*4 + hi4)*144 + lo16))*8;
      #pragma unroll
      for (int mt = 0; mt < MT; ++mt) {
        short8 bh = *reinterpret_cast<const short8*>(bpH + mt*128);
        acc[mt] = __builtin_amdgcn_mfma_f32_16x16x32_bf16(whi, bh, acc[mt], 0, 0, 0);
        acc[mt] = __builtin_amdgcn_mfma_f32_16x16x32_bf16(wlo, bh, acc[mt], 0, 0, 0);
      }
      __syncthreads();                 // L staged; H free
      // stage bh(step+1) -> H (async, hides under consume-L)
      if (step < 7) {
        const size_t kAdv2 = kAdv + (size_t)4*ROWS_MAX*8;
        gload_lds16(ws->aHiT + off0 + kAdv2, sH + (size_t)tid*8);
        gload_lds16(ws->aHiT + off1 + kAdv2, sH + (size_t)(tid + 512)*8);
        if (v2) gload_lds16(ws->aHiT + off2 + kAdv2, sH + (size_t)(tid + 1024)*8);
      }
      // consume L: lo-operand product (whi*bl)
      const unsigned short* bpL = sLb + ((size_t)((kh*4 + hi4)*144 + lo16))*8;
      #pragma unroll
      for (int mt = 0; mt < MT; ++mt) {
        short8 bl = *reinterpret_cast<const short8*>(bpL + mt*128);
        acc[mt] = __builtin_amdgcn_mfma_f32_16x16x32_bf16(whi, bl, acc[mt], 0, 0, 0);
      }
      __syncthreads();                 // H staged for next step; L free
    }

    // ---- combine k-halves through LDS (smem reused as sAcc/sEs/sMx) ----
    if (kh == 1) {
      #pragma unroll
      for (int mt = 0; mt < MT; ++mt) sAcc[sub][mt][lane] = acc[mt];
    }
    __syncthreads();

    if (kh == 0) {
      // epilogue: D[m=c-local=(hi4*4+v)][n=row=lo16]; tgt from aminS
      #pragma unroll
      for (int mt = 0; mt < MT; ++mt) {
        const int row = r0 + mt*16 + lo16;
        int tgt = -1;
        if (row < nA) {
          const unsigned long long* ap = ws->aminS + (size_t)(row*NG + g)*QS;
          unsigned long long m = ap[0];
          #pragma unroll
          for (int s2 = 1; s2 < QS; ++s2) {
            unsigned long long v = ap[s2];
            if (v < m) m = v;
          }
          tgt = (int)(unsigned)(m & 0xFFFFFFFFull);
          if (blockIdx.x == 0 && wave == 0 && hi4 == 0)
            ws->targets[row*NG + g] = tgt;
        }
        f32x4 oth = sAcc[sub][mt][lane];
        float lv[4];
        #pragma unroll
        for (int v = 0; v < 4; ++v) lv[v] = (acc[mt][v] + oth[v]) + bv[v];
        #pragma unroll
        for (int v = 0; v < 4; ++v)
          if (tgt == cOut0 + v) ws->tLogit[row*NG + g] = lv[v];
        float es = expf(lv[0]) + expf(lv[1]) + expf(lv[2]) + expf(lv[3]);
        float mv = lv[0]; int mi = cOut0;
        if (lv[1] > mv) { mv = lv[1]; mi = cOut0+1; }
        if (lv[2] > mv) { mv = lv[2]; mi = cOut0+2; }
        if (lv[3] > mv) { mv = lv[3]; mi = cOut0+3; }
        #pragma unroll
        for (int off = 16; off <= 32; off <<= 1) {
          es += __shfl_xor(es, off);
          float ov = __shfl_xor(mv, off);
          int   oi = __shfl_xor(mi, off);
          if (ov > mv || (ov == mv && oi < mi)) { mv = ov; mi = oi; }
        }
        if (hi4 == 0) {
          sEs[sub][mt*16 + lo16] = es;
          unsigned key = __float_as_uint(mv);
          key = (key & 0x80000000u) ? ~key : (key | 0x80000000u);
          sMx[sub][mt*16 + lo16] = ((unsigned long long)key << 32)
                                 | (unsigned long long)(0xFFFFFFFFu - (unsigned)mi);
        }
      }
    }
    __syncthreads();
    if (tid < ROWCH) {
      float e = sEs[0][tid] + sEs[1][tid] + sEs[2][tid] + sEs[3][tid];
      unsigned long long m0 = sMx[0][tid], m1 = sMx[1][tid];
      unsigned long long m2 = sMx[2][tid], m3 = sMx[3][tid];
      unsigned long long ma = m0 > m1 ? m0 : m1;
      unsigned long long mb = m2 > m3 ? m2 : m3;
      unsigned long long mx = ma > mb ? ma : mb;
      int grow = r0 + tid;
      ws->part_se[g][grow][blockIdx.x] = e;
      ws->part_mx[g][grow][blockIdx.x] = mx;
    }
    __syncthreads();
  }
}

// ---- reduce 128 c-tile partials per (row,g): plain stores, no atomics ----
__global__ __launch_bounds__(256) void k_red_l(Ws* ws) {
  int nA = (int)ws->nA;
  int pair = blockIdx.x*4 + (threadIdx.x >> 6);
  int lane = threadIdx.x & 63;
  int row = pair >> 2, g = pair & 3;
  if (row >= nA) return;
  float e = ws->part_se[g][row][lane] + ws->part_se[g][row][lane + 64];
  unsigned long long a = ws->part_mx[g][row][lane];
  unsigned long long b = ws->part_mx[g][row][lane + 64];
  unsigned long long mx = a > b ? a : b;
  #pragma unroll
  for (int off = 32; off; off >>= 1) {
    e += __shfl_xor(e, off);
    unsigned long long o = __shfl_xor(mx, off);
    if (o > mx) mx = o;
  }
  if (lane == 0) {
    ws->sumExp[row*NG + g] = e;
    ws->amax[row*NG + g] = mx;
  }
}

// ======================= fallback fp32 path (round-1, proven) ==============
__global__ __launch_bounds__(256) void k_quant(
    const float* __restrict__ feats, const float* __restrict__ mean,
    const float* __restrict__ istd, const float* __restrict__ projw,
    const float* __restrict__ emb, Ws* ws) {
  if (blockIdx.x >= ws->nA) return;
  int ai = blockIdx.x;
  int p = ws->activeList[ai];
  int b = p >> 8, ts = p & (NTS-1);
  int tid = threadIdx.x;
  __shared__ float sN[SFD];
  __shared__ float sPart[4*64];
  __shared__ float sLat[NG*NE];
  __shared__ float sRedS[256];
  __shared__ int   sRedC[256];
  __shared__ float rS[4], rQ[4];
  __shared__ int   sTgt[NG];

  for (int j = tid; j < SFD; j += 256) {
    int k = j / NF, f = j - k*NF;
    sN[j] = (feats[((size_t)b*NT + ts*NSTRIDE + k)*NF + f] - mean[f]) * istd[f];
  }
  __syncthreads();
  float s = 0.f, q = 0.f;
  for (int j = tid; j < SFD; j += 256) { float x = sN[j]; s += x; q += x*x; }
  for (int o = 32; o; o >>= 1) { s += __shfl_down(s, o); q += __shfl_down(q, o); }
  if ((tid & 63) == 0) { rS[tid>>6] = s; rQ[tid>>6] = q; }
  __syncthreads();
  float mu  = (rS[0]+rS[1]+rS[2]+rS[3]) * (1.f/SFD);
  float var = (rQ[0]+rQ[1]+rQ[2]+rQ[3]) * (1.f/SFD) - mu*mu;
  float inv = rsqrtf(var + LNEPS);
  for (int j = tid; j < SFD; j += 256) sN[j] = (sN[j]-mu)*inv;
  __syncthreads();
  {
    int j = tid & 63, part = tid >> 6;
    float a = 0.f;
    int i0 = part*80;
    for (int i = i0; i < i0+80; ++i) a = fmaf(sN[i], projw[i*64 + j], a);
    sPart[part*64 + j] = a;
  }
  __syncthreads();
  if (tid < 64) sLat[tid] = sPart[tid] + sPart[64+tid] + sPart[128+tid] + sPart[192+tid];
  __syncthreads();

  for (int gg = 0; gg < NG; ++gg) {
    float lg[NE];
    #pragma unroll
    for (int e = 0; e < NE; ++e) lg[e] = sLat[gg*NE + e];
    float best = 3.4e38f; int bc = NC;
    for (int c = tid; c < NC; c += 256) {
      const float4* cb4 = reinterpret_cast<const float4*>(emb + ((size_t)c*NG + gg)*NE);
      float4 a0 = cb4[0], a1 = cb4[1], a2 = cb4[2], a3 = cb4[3];
      float dot = 0.f, n2 = 0.f;
      dot = fmaf(lg[0],  a0.x, dot); n2 = fmaf(a0.x, a0.x, n2);
      dot = fmaf(lg[1],  a0.y, dot); n2 = fmaf(a0.y, a0.y, n2);
      dot = fmaf(lg[2],  a0.z, dot); n2 = fmaf(a0.z, a0.z, n2);
      dot = fmaf(lg[3],  a0.w, dot); n2 = fmaf(a0.w, a0.w, n2);
      dot = fmaf(lg[4],  a1.x, dot); n2 = fmaf(a1.x, a1.x, n2);
      dot = fmaf(lg[5],  a1.y, dot); n2 = fmaf(a1.y, a1.y, n2);
      dot = fmaf(lg[6],  a1.z, dot); n2 = fmaf(a1.z, a1.z, n2);
      dot = fmaf(lg[7],  a1.w, dot); n2 = fmaf(a1.w, a1.w, n2);
      dot = fmaf(lg[8],  a2.x, dot); n2 = fmaf(a2.x, a2.x, n2);
      dot = fmaf(lg[9],  a2.y, dot); n2 = fmaf(a2.y, a2.y, n2);
      dot = fmaf(lg[10], a2.z, dot); n2 = fmaf(a2.z, a2.z, n2);
      dot = fmaf(lg[11], a2.w, dot); n2 = fmaf(a2.w, a2.w, n2);
      dot = fmaf(lg[12], a3.x, dot); n2 = fmaf(a3.x, a3.x, n2);
      dot = fmaf(lg[13], a3.y, dot); n2 = fmaf(a3.y, a3.y, n2);
      dot = fmaf(lg[14], a3.z, dot); n2 = fmaf(a3.z, a3.z, n2);
      dot = fmaf(lg[15], a3.w, dot); n2 = fmaf(a3.w, a3.w, n2);
      float sc = n2 - 2.f*dot;
      if (sc < best) { best = sc; bc = c; }
    }
    sRedS[tid] = best; sRedC[tid] = bc;
    __syncthreads();
    for (int off = 128; off; off >>= 1) {
      if (tid < off) {
        float os = sRedS[tid+off]; int oc = sRedC[tid+off];
        if (os < sRedS[tid] || (os == sRedS[tid] && oc < sRedC[tid])) {
          sRedS[tid] = os; sRedC[tid] = oc;
        }
      }
      __syncthreads();
    }
    if (tid == 0) sTgt[gg] = sRedC[0];
    __syncthreads();
  }
  if (tid < NG) ws->targets[ai*NG + tid] = sTgt[tid];
}

__global__ __launch_bounds__(256) void k_logits(
    const float* __restrict__ W, const float* __restrict__ bias,
    const float* __restrict__ enc, Ws* ws) {
  const int nA = (int)ws->nA;
  if (nA == 0) return;
  const int nCh = (nA + PCH - 1) / PCH;
  const int g = blockIdx.y;
  const int cbase = blockIdx.x * TCC + threadIdx.x * CPT;
  const float* __restrict__ Wg = W + (size_t)g*ND*NC;
  const float b0 = bias[g*NC + cbase + 0];
  const float b1 = bias[g*NC + cbase + 1];
  const float b2 = bias[g*NC + cbase + 2];
  const float b3 = bias[g*NC + cbase + 3];
  __shared__ float4 sEnc[PCH][ND/4];
  __shared__ int sP[PCH];

  for (int ch = blockIdx.z; ch < nCh; ch += PB) {
    if (threadIdx.x < PCH) {
      int ai = ch*PCH + threadIdx.x;
      sP[threadIdx.x] = (ai < nA) ? ws->activeList[ai] : -1;
    }
    __syncthreads();
    for (int i = threadIdx.x; i < PCH*(ND/4); i += 256) {
      int qq = i >> 7, r = i & 127;
      int p = sP[qq];
      sEnc[qq][r] = (p >= 0) ? reinterpret_cast<const float4*>(enc)[p*(ND/4) + r]
                             : make_float4(0.f, 0.f, 0.f, 0.f);
    }
    __syncthreads();

    float acc[PCH][CPT];
    #pragma unroll
    for (int qq = 0; qq < PCH; ++qq)
      #pragma unroll
      for (int j = 0; j < CPT; ++j) acc[qq][j] = 0.f;
    for (int d = 0; d < ND; d += 4) {
      const float* wp = Wg + (size_t)d*NC + cbase;
      float4 w0 = *reinterpret_cast<const float4*>(wp);
      float4 w1 = *reinterpret_cast<const float4*>(wp + NC);
      float4 w2 = *reinterpret_cast<const float4*>(wp + 2*NC);
      float4 w3 = *reinterpret_cast<const float4*>(wp + 3*NC);
      int dq = d >> 2;
      #pragma unroll
      for (int qq = 0; qq < PCH; ++qq) {
        float4 e = sEnc[qq][dq];
        acc[qq][0] = fmaf(e.x, w0.x, acc[qq][0]);
        acc[qq][1] = fmaf(e.x, w0.y, acc[qq][1]);
        acc[qq][2] = fmaf(e.x, w0.z, acc[qq][2]);
        acc[qq][3] = fmaf(e.x, w0.w, acc[qq][3]);
        acc[qq][0] = fmaf(e.y, w1.x, acc[qq][0]);
        acc[qq][1] = fmaf(e.y, w1.y, acc[qq][1]);
        acc[qq][2] = fmaf(e.y, w1.z, acc[qq][2]);
        acc[qq][3] = fmaf(e.y, w1.w, acc[qq][3]);
        acc[qq][0] = fmaf(e.z, w2.x, acc[qq][0]);
        acc[qq][1] = fmaf(e.z, w2.y, acc[qq][1]);
        acc[qq][2] = fmaf(e.z, w2.z, acc[qq][2]);
        acc[qq][3] = fmaf(e.z, w2.w, acc[qq][3]);
        acc[qq][0] = fmaf(e.w, w3.x, acc[qq][0]);
        acc[qq][1] = fmaf(e.w, w3.y, acc[qq][1]);
        acc[qq][2] = fmaf(e.w, w3.z, acc[qq][2]);
        acc[qq][3] = fmaf(e.w, w3.w, acc[qq][3]);
      }
    }

    #pragma unroll
    for (int qq = 0; qq < PCH; ++qq) {
      int ai = ch*PCH + qq;
      if (ai < nA) {
        float l0 = acc[qq][0] + b0;
        float l1 = acc[qq][1] + b1;
        float l2 = acc[qq][2] + b2;
        float l3 = acc[qq][3] + b3;
        int tgt = ws->targets[ai*NG + g];
        if ((unsigned)(tgt - cbase) < (unsigned)CPT) {
          float tv = (tgt == cbase) ? l0 : (tgt == cbase+1) ? l1
                   : (tgt == cbase+2) ? l2 : l3;
          ws->tLogit[ai*NG + g] = tv;
        }
        float es = expf(l0) + expf(l1) + expf(l2) + expf(l3);
        float mv = l0; int mi = cbase;
        if (l1 > mv) { mv = l1; mi = cbase+1; }
        if (l2 > mv) { mv = l2; mi = cbase+2; }
        if (l3 > mv) { mv = l3; mi = cbase+3; }
        for (int o = 32; o; o >>= 1) {
          es += __shfl_down(es, o);
          float ov = __shfl_down(mv, o);
          int   oi = __shfl_down(mi, o);
          if (ov > mv || (ov == mv && oi < mi)) { mv = ov; mi = oi; }
        }
        if ((threadIdx.x & 63) == 0) {
          atomicAdd(&ws->sumExp[ai*NG + g], es);
          unsigned key = __float_as_uint(mv);
          key = (key & 0x80000000u) ? ~key : (key | 0x80000000u);
          unsigned long long pk =
              ((unsigned long long)key << 32) |
              (unsigned long long)(0xFFFFFFFFu - (unsigned)mi);
          atomicMax(&ws->amax[ai*NG + g], pk);
        }
      }
    }
    __syncthreads();
  }
}
// ======================= end fallback =======================================

// ---- final scalar assembly (uniq bitmap built in LDS from targets) ----
__global__ __launch_bounds__(256) void k_final(Ws* ws, float* __restrict__ out) {
  int tid = threadIdx.x;
  int nA = (int)ws->nA;
  __shared__ unsigned sbm[NC/32];   // 256 words == blockDim
  sbm[tid] = 0u;
  __syncthreads();

  float sumPer = 0.f, sumCorr = 0.f;
  for (int i = tid; i < nA*NG; i += 256) {
    int tgt = ws->targets[i];
    sumPer += logf(ws->sumExp[i]) - ws->tLogit[i];
    unsigned long long pk = ws->amax[i];
    int mi = (int)(0xFFFFFFFFu - (unsigned)(pk & 0xFFFFFFFFull));
    if (mi == tgt) sumCorr += 1.f;
    atomicOr(&sbm[tgt >> 5], 1u << (tgt & 31));
  }
  __syncthreads();
  unsigned w = sbm[tid];
  if (tid == 0 && nA < NP) w |= 1u;   // masked positions contribute code 0
  int uniq = __popc(w);

  __shared__ float rs[4], rc[4]; __shared__ int ru[4];
  float s1 = sumPer, s2 = sumCorr; int s3 = uniq;
  for (int o = 32; o; o >>= 1) {
    s1 += __shfl_down(s1, o);
    s2 += __shfl_down(s2, o);
    s3 += __shfl_down(s3, o);
  }
  if ((tid & 63) == 0) { rs[tid>>6] = s1; rc[tid>>6] = s2; ru[tid>>6] = s3; }
  __syncthreads();
  if (tid == 0) {
    float sp = rs[0]+rs[1]+rs[2]+rs[3];
    float sc = rc[0]+rc[1]+rc[2]+rc[3];
    int   un = ru[0]+ru[1]+ru[2]+ru[3];
    float pen   = ws->penSum / (float)(NB*NT*NF);
    float denom = (float)nA + 1e-5f;
    float nc    = (float)(nA * NG);
    out[0] = sp / (denom * (float)NG) + FREG * pen;
    out[1] = sc / nc;
    out[2] = pen;
    out[3] = nc;
    out[4] = (float)un;
  }
}

extern "C" void kernel_launch(void* const* d_in, const int* in_sizes, int n_in,
                              void* d_out, int out_size, void* d_ws, size_t ws_size,
                              hipStream_t stream) {
  const float* feats = (const float*)d_in[0];
  const int*   lens  = (const int*)d_in[1];
  const unsigned char* masks = (const unsigned char*)d_in[2];
  const float* mean  = (const float*)d_in[4];
  const float* istd  = (const float*)d_in[5];
  const float* projw = (const float*)d_in[6];
  const float* emb   = (const float*)d_in[7];
  const float* W     = (const float*)d_in[8];
  const float* bias  = (const float*)d_in[9];
  const float* enc   = (const float*)d_in[10];
  Ws* ws = (Ws*)d_ws;
  float* out = (float*)d_out;

  bool big = ws_size >= sizeof(Ws);
  if (big) {
    k_zero<<<1, 64, 0, stream>>>(ws);
    k_prologue<<<256, 256, 0, stream>>>(feats, mean, istd, masks, lens, 1, ws);
    k_latprep<<<ROWS_MAX, 256, 0, stream>>>(feats, mean, istd, projw, enc, ws);
    k_qdist<<<dim3(NC/64, QY), 256, 0, stream>>>(emb, ws);
    k_logits_mfma<<<dim3(CT, NG), 512, 0, stream>>>(W, bias, ws);
    k_red_l<<<NP, 256, 0, stream>>>(ws);
  } else {
    size_t zr = offsetof(Ws, aminS);
    hipMemsetAsync(d_ws, 0, ws_size < zr ? ws_size : zr, stream);
    k_prologue<<<256, 256, 0, stream>>>(feats, mean, istd, masks, lens, 0, ws);
    k_quant<<<NP, 256, 0, stream>>>(feats, mean, istd, projw, emb, ws);
    k_logits<<<dim3(NC/TCC, NG, PB), 256, 0, stream>>>(W, bias, enc, ws);
  }
  k_final<<<1, 256, 0, stream>>>(ws, out);
}

// Round 12
// 74.820 us; speedup vs baseline: 1.0377x; 1.0377x over previous
//
#include <hip/hip_runtime.h>
#include <hip/hip_bf16.h>
#include <math.h>
#include <stddef.h>

// Problem constants (from reference)
#define NB 8
#define NT 1024
#define NF 80
#define NSTACK 4
#define NSTRIDE 4
#define NG 4
#define NE 16
#define NC 8192
#define ND 512
#define NTS 256          // (NT-NSTACK)/NSTRIDE + 1
#define NP (NB*NTS)      // 2048 subsampled positions
#define SFD (NSTACK*NF)  // 320
#define FREG 0.01f
#define LNEPS 1e-5f

// fp32-fallback k_logits tiling
#define TCC 1024
#define CPT 4
#define PCH 16
#define PB 16

// MFMA path
#define ROWS_MAX 2176     // >= ceil(2048/144)*144 = 2160
#define ROWCH 144         // rows per chunk (all in acc regs)
#define MT 9              // 16-row m-tiles per chunk
#define QCH 16            // lat rows staged per k_qdist pass (4 KB LDS)
#define QY 32             // k_qdist row-split factor (grid.y)
#define CT 128            // c-tiles of 64 for the logits GEMM partials
#define QS 8              // qdist atomic spread slots
#define STG16H 1152       // 16B chunks per HALF stage (2 kh x 4 hi4 x 144 rows)

typedef __attribute__((ext_vector_type(8))) short short8;
typedef __attribute__((ext_vector_type(4))) float f32x4;

struct Ws {
  // header
  float penSum;                     // fallback only (atomics)
  unsigned int nA;                  // plain-stored by k_prologue block 0
  unsigned int maskIsInt;
  unsigned int pad1;
  unsigned long long amax[NP*NG];   // plain-stored by k_red_l (big) / atomics (fallback)
  float sumExp[NP*NG];
  float tLogit[NP*NG];
  int   targets[NP*NG];
  int   activeList[NP];
  float penPart[256];               // per-block pen partials (plain stores)
  // initialized by k_prologue (big path)
  unsigned long long aminS[NP*NG*QS]; // qdist spread argmin slots (0xFF)
  // no init needed
  float lat[NP][64];
  // fragment-order bf16 splits: aHiT[((k/8)*ROWS_MAX + row)*8 + (k%8)]
  unsigned short aHiT[(size_t)(ND/8)*ROWS_MAX*8];
  unsigned short aLoT[(size_t)(ND/8)*ROWS_MAX*8];
  float part_se[NG][ROWS_MAX][CT];
  unsigned long long part_mx[NG][ROWS_MAX][CT];
};

__device__ inline unsigned short bf16_rne(float x) {
  unsigned u = __float_as_uint(x);
  unsigned r = u + 0x7FFFu + ((u >> 16) & 1u);
  return (unsigned short)(r >> 16);
}
__device__ inline unsigned fkey_asc(float d) {  // ascending float -> ascending uint
  unsigned u = __float_as_uint(d);
  return (u & 0x80000000u) ? ~u : (u | 0x80000000u);
}
__device__ __forceinline__ void gload_lds16(const void* g, void* l) {
  __builtin_amdgcn_global_load_lds(
      (const __attribute__((address_space(1))) void*)g,
      (__attribute__((address_space(3))) void*)l, 16, 0, 0);
}

// ---- fused prologue: pen partials + deterministic compact + aminS init ----
// grid 256 x 256. All blocks: pen grid-stride partial -> penPart[blockIdx],
// plus clear 1 aminS entry/thread. Block 0: mask-layout detect + prefix-sum
// compaction of the 2048 positions (plain stores of nA/activeList).
__global__ __launch_bounds__(256) void k_prologue(
    const float* __restrict__ feats, const float* __restrict__ mean,
    const float* __restrict__ istd, const unsigned char* __restrict__ m8,
    const int* __restrict__ lens, int doClear, Ws* ws) {
  const int tid = threadIdx.x;
  if (doClear) ws->aminS[(size_t)blockIdx.x*256 + tid] = ~0ull;

  // features_pen partial
  const int N4 = NB*NT*NF/4;
  float s = 0.f;
  for (int i = blockIdx.x*256 + tid; i < N4; i += gridDim.x*256) {
    float4 v = reinterpret_cast<const float4*>(feats)[i];
    int f0 = (i*4) % NF;
    float x0 = (v.x - mean[f0+0]) * istd[f0+0];
    float x1 = (v.y - mean[f0+1]) * istd[f0+1];
    float x2 = (v.z - mean[f0+2]) * istd[f0+2];
    float x3 = (v.w - mean[f0+3]) * istd[f0+3];
    s += x0*x0 + x1*x1 + x2*x2 + x3*x3;
  }
  for (int o = 32; o; o >>= 1) s += __shfl_down(s, o);
  __shared__ float pr[4];
  if ((tid & 63) == 0) pr[tid >> 6] = s;
  __syncthreads();
  if (tid == 0) ws->penPart[blockIdx.x] = pr[0]+pr[1]+pr[2]+pr[3];

  // block 0: detect + deterministic compaction (prefix sum, plain stores)
  if (blockIdx.x == 0) {
    __shared__ unsigned flag;
    __shared__ int sCnt[256];
    if (tid == 0) flag = 0;
    __syncthreads();
    unsigned nz = 0;
    int base = tid * 32;
    for (int i = base; i < base + 32; ++i)
      if ((i & 3) && m8[i]) nz = 1;
    if (nz) atomicOr(&flag, 1u);   // LDS atomic, no pre-zero of global needed
    __syncthreads();
    bool isInt = (flag == 0);
    const int* m32 = (const int*)m8;

    unsigned bits = 0;
    int cnt = 0;
    #pragma unroll
    for (int j = 0; j < 8; ++j) {
      int p = tid*8 + j;
      int b = p >> 8, ts = p & (NTS-1);
      int t0 = b*NT + ts*NSTRIDE;
      bool allm;
      if (isInt) allm = m32[t0] && m32[t0+1] && m32[t0+2] && m32[t0+3];
      else       allm = m8[t0] && m8[t0+1] && m8[t0+2] && m8[t0+3];
      int ls = (lens[b] - NSTACK)/NSTRIDE + 1;
      if (ls < 0) ls = 0;
      bool act = allm && (ts < ls);
      bits |= (unsigned)act << j;
      cnt += act;
    }
    sCnt[tid] = cnt;
    __syncthreads();
    // Hillis-Steele inclusive scan over 256 counts
    #pragma unroll
    for (int off = 1; off < 256; off <<= 1) {
      int v = (tid >= off) ? sCnt[tid - off] : 0;
      __syncthreads();
      sCnt[tid] += v;
      __syncthreads();
    }
    int wr = sCnt[tid] - cnt;     // exclusive prefix
    #pragma unroll
    for (int j = 0; j < 8; ++j) {
      if (bits & (1u << j)) ws->activeList[wr++] = tid*8 + j;
    }
    if (tid == 255) ws->nA = (unsigned)sCnt[255];
  }
}

// ---- fused: latents (stack+LN+proj) AND fragment-order enc bf16 split ----
__global__ __launch_bounds__(256) void k_latprep(
    const float* __restrict__ feats, const float* __restrict__ mean,
    const float* __restrict__ istd, const float* __restrict__ projw,
    const float* __restrict__ enc, Ws* ws) {
  int nA = (int)ws->nA;
  int ai = blockIdx.x;
  int limit = ((nA + ROWCH - 1) / ROWCH) * ROWCH;
  int tid = threadIdx.x;

  if (ai >= nA) {
    if (ai < limit && tid < 64) {     // zero-pad fragment rows
      short8 z;
      #pragma unroll
      for (int j = 0; j < 8; ++j) z[j] = 0;
      *reinterpret_cast<short8*>(ws->aHiT + ((size_t)tid*ROWS_MAX + ai)*8) = z;
      *reinterpret_cast<short8*>(ws->aLoT + ((size_t)tid*ROWS_MAX + ai)*8) = z;
    }
    return;
  }

  int p = ws->activeList[ai];
  if (tid < 64) {
    const float* src = enc + (size_t)p*ND + tid*8;
    float4 x0 = *reinterpret_cast<const float4*>(src);
    float4 x1 = *reinterpret_cast<const float4*>(src + 4);
    float xv[8] = {x0.x, x0.y, x0.z, x0.w, x1.x, x1.y, x1.z, x1.w};
    short8 h, l;
    #pragma unroll
    for (int j = 0; j < 8; ++j) {
      unsigned short hi = bf16_rne(xv[j]);
      float rem = xv[j] - __uint_as_float((unsigned)hi << 16);
      h[j] = (short)hi;
      l[j] = (short)bf16_rne(rem);
    }
    *reinterpret_cast<short8*>(ws->aHiT + ((size_t)tid*ROWS_MAX + ai)*8) = h;
    *reinterpret_cast<short8*>(ws->aLoT + ((size_t)tid*ROWS_MAX + ai)*8) = l;
  }

  int b = p >> 8, ts = p & (NTS-1);
  __shared__ float sN[SFD];
  __shared__ float sPart[4*64];
  __shared__ float rS[4], rQ[4];

  for (int j = tid; j < SFD; j += 256) {
    int k = j / NF, f = j - k*NF;
    sN[j] = (feats[((size_t)b*NT + ts*NSTRIDE + k)*NF + f] - mean[f]) * istd[f];
  }
  __syncthreads();
  float s = 0.f, q = 0.f;
  for (int j = tid; j < SFD; j += 256) { float x = sN[j]; s += x; q += x*x; }
  for (int o = 32; o; o >>= 1) { s += __shfl_down(s, o); q += __shfl_down(q, o); }
  if ((tid & 63) == 0) { rS[tid>>6] = s; rQ[tid>>6] = q; }
  __syncthreads();
  float mu  = (rS[0]+rS[1]+rS[2]+rS[3]) * (1.f/SFD);
  float var = (rQ[0]+rQ[1]+rQ[2]+rQ[3]) * (1.f/SFD) - mu*mu;
  float inv = rsqrtf(var + LNEPS);
  for (int j = tid; j < SFD; j += 256) sN[j] = (sN[j]-mu)*inv;
  __syncthreads();
  {
    int j = tid & 63, part = tid >> 6;
    float a = 0.f;
    int i0 = part*80;
    for (int i = i0; i < i0+80; ++i) a = fmaf(sN[i], projw[i*64 + j], a);
    sPart[part*64 + j] = a;
  }
  __syncthreads();
  if (tid < 64)
    ws->lat[ai][tid] = sPart[tid] + sPart[64+tid] + sPart[128+tid] + sPart[192+tid];
}

// ---- codebook argmin, c-parallel, 32-way row-split; spread atomicMin ----
__global__ __launch_bounds__(256) void k_qdist(const float* __restrict__ emb, Ws* ws) {
  int nA = (int)ws->nA;
  if (nA == 0) return;
  int tid = threadIdx.x;
  int g = tid >> 6, lane = tid & 63;
  int c = blockIdx.x * 64 + lane;
  int per = (nA + QY - 1) / QY;
  int a0 = blockIdx.y * per;
  int a1 = min(nA, a0 + per);
  int slot = blockIdx.x & (QS-1);

  const float4* e4 = reinterpret_cast<const float4*>(emb + ((size_t)c*NG + g)*NE);
  float4 b0 = e4[0], b1 = e4[1], b2 = e4[2], b3 = e4[3];
  float n2 = b0.x*b0.x + b0.y*b0.y + b0.z*b0.z + b0.w*b0.w
           + b1.x*b1.x + b1.y*b1.y + b1.z*b1.z + b1.w*b1.w
           + b2.x*b2.x + b2.y*b2.y + b2.z*b2.z + b2.w*b2.w
           + b3.x*b3.x + b3.y*b3.y + b3.z*b3.z + b3.w*b3.w;

  __shared__ float sL[QCH][64];
  for (int base = a0; base < a1; base += QCH) {
    int cnt = min(QCH, a1 - base);
    __syncthreads();
    for (int i = tid; i < cnt*64; i += 256)
      (&sL[0][0])[i] = (&ws->lat[0][0])[(size_t)(base + (i >> 6))*64 + (i & 63)];
    __syncthreads();
    for (int i = 0; i < cnt; ++i) {
      const float* lp = &sL[i][g*NE];
      float dot = lp[0]*b0.x + lp[1]*b0.y + lp[2]*b0.z + lp[3]*b0.w
                + lp[4]*b1.x + lp[5]*b1.y + lp[6]*b1.z + lp[7]*b1.w
                + lp[8]*b2.x + lp[9]*b2.y + lp[10]*b2.z + lp[11]*b2.w
                + lp[12]*b3.x + lp[13]*b3.y + lp[14]*b3.z + lp[15]*b3.w;
      float d = n2 - 2.f*dot;
      float mv = d; int mc = c;
      #pragma unroll
      for (int off = 32; off; off >>= 1) {
        float ov = __shfl_xor(mv, off);
        int   oc = __shfl_xor(mc, off);
        if (ov < mv || (ov == mv && oc < mc)) { mv = ov; mc = oc; }
      }
      if (lane == 0) {
        unsigned long long key =
            ((unsigned long long)fkey_asc(mv) << 32) | (unsigned)mc;
        atomicMin(&ws->aminS[(size_t)((base + i)*NG + g)*QS + slot], key);
      }
    }
  }
}

// ---- logits GEMM: W read+split once (A-operand, 1-step register prefetch so
// converts never stall), enc fragment-order (B-operand) in split H/L LDS
// buffers (pipelined), in-block K-split across waves, fused target extract ----
__global__ __launch_bounds__(512, 4) void k_logits_mfma(
    const float* __restrict__ W, const float* __restrict__ bias, Ws* ws) {
  const int nA = (int)ws->nA;
  if (nA == 0) return;
  const int nCh = (nA + ROWCH - 1) / ROWCH;
  const int tid = threadIdx.x;
  const int wave = tid >> 6, lane = tid & 63;
  const int sub = wave & 3, kh = wave >> 2;
  const int g = blockIdx.y;
  const int c0w = blockIdx.x * 64 + sub * 16;
  const int lo16 = lane & 15, hi4 = lane >> 4;
  const int cA = c0w + lo16;           // A-fragment column
  const int cOut0 = c0w + hi4*4;       // this lane's 4 output c's
  float bv[4];
  #pragma unroll
  for (int v = 0; v < 4; ++v) bv[v] = bias[g*NC + cOut0 + v];

  // Union region: k-loop -> H (18432) + L (18432) stage buffers;
  // epilogue -> sAcc (36864) + sEs (2304 pad 2560) + sMx (4608).
  __shared__ __align__(16) unsigned char smem[45056];
  unsigned short* sH = (unsigned short*)smem;
  unsigned short* sLb = (unsigned short*)(smem + 18432);
  f32x4 (*sAcc)[MT][64] = (f32x4 (*)[MT][64])smem;
  float (*sEs)[ROWCH] = (float (*)[ROWCH])(smem + 36864);
  unsigned long long (*sMx)[ROWCH] =
      (unsigned long long (*)[ROWCH])(smem + 36864 + 2560);

  // W base for this wave's k-half: k = kh*256 + step*32 + hi4*8
  const float* __restrict__ wBase =
      W + (((size_t)g*ND + (size_t)kh*256 + hi4*8)*NC) + cA;

  for (int ch = 0; ch < nCh; ++ch) {
    const int r0 = ch * ROWCH;

    // per-thread half-stage source offsets (shorts): t -> (khh,h4,row)
    size_t off0, off1, off2; bool v2;
    {
      int t = tid;                         // < 512
      int part = t/144, row = t - part*144;
      off0 = ((size_t)((part>>2)*32 + (part&3))*ROWS_MAX + r0 + row)*8;
      t = tid + 512;                       // < 1024
      part = t/144; row = t - part*144;
      off1 = ((size_t)((part>>2)*32 + (part&3))*ROWS_MAX + r0 + row)*8;
      t = tid + 1024;
      v2 = (t < STG16H);
      part = t/144; row = t - part*144;
      off2 = v2 ? ((size_t)((part>>2)*32 + (part&3))*ROWS_MAX + r0 + row)*8 : 0;
    }

    f32x4 acc[MT];
    #pragma unroll
    for (int mt = 0; mt < MT; ++mt) acc[mt] = (f32x4){0.f, 0.f, 0.f, 0.f};

    // stage bh(0) -> H ; W(0) -> regs (both drained by the barrier)
    gload_lds16(ws->aHiT + off0, sH + (size_t)tid*8);
    gload_lds16(ws->aHiT + off1, sH + (size_t)(tid + 512)*8);
    if (v2) gload_lds16(ws->aHiT + off2, sH + (size_t)(tid + 1024)*8);
    float wv[8];
    #pragma unroll
    for (int j = 0; j < 8; ++j) wv[j] = wBase[(size_t)j*NC];
    __syncthreads();

    #pragma unroll 1
    for (int step = 0; step < 8; ++step) {
      const size_t kAdv = (size_t)step*4*ROWS_MAX*8;
      // stage bl(step) -> L (async, hides under consume-H)
      gload_lds16(ws->aLoT + off0 + kAdv, sLb + (size_t)tid*8);
      gload_lds16(ws->aLoT + off1 + kAdv, sLb + (size_t)(tid + 512)*8);
      if (v2) gload_lds16(ws->aLoT + off2 + kAdv, sLb + (size_t)(tid + 1024)*8);
      // convert current W (already in regs: prefetched last step) -> no stall
      short8 whi, wlo;
      #pragma unroll
      for (int j = 0; j < 8; ++j) {
        unsigned short h = bf16_rne(wv[j]);
        float rem = wv[j] - __uint_as_float((unsigned)h << 16);
        whi[j] = (short)h;
        wlo[j] = (short)bf16_rne(rem);
      }
      // consume H: hi-operand products (whi*bh, wlo*bh)
      const unsigned short* bpH = sH + ((size_t)((kh*4 + hi4)*144 + lo16))*8;
      #pragma unroll
      for (int mt = 0; mt < MT; ++mt) {
        short8 bh = *reinterpret_cast<const short8*>(bpH + mt*128);
        acc[mt] = __builtin_amdgcn_mfma_f32_16x16x32_bf16(whi, bh, acc[mt], 0, 0, 0);
        acc[mt] = __builtin_amdgcn_mfma_f32_16x16x32_bf16(wlo, bh, acc[mt], 0, 0, 0);
      }
      __syncthreads();                 // L staged; H free
      // stage bh(step+1) -> H and prefetch W(step+1) (both drained by barrier2)
      float wvn[8];
      if (step < 7) {
        const size_t kAdv2 = kAdv + (size_t)4*ROWS_MAX*8;
        gload_lds16(ws->aHiT + off0 + kAdv2, sH + (size_t)tid*8);
        gload_lds16(ws->aHiT + off1 + kAdv2, sH + (size_t)(tid + 512)*8);
        if (v2) gload_lds16(ws->aHiT + off2 + kAdv2, sH + (size_t)(tid + 1024)*8);
        const float* wpn = wBase + (size_t)(step+1)*32*NC;
        #pragma unroll
        for (int j = 0; j < 8; ++j) wvn[j] = wpn[(size_t)j*NC];
      }
      // consume L: lo-operand product (whi*bl)
      const unsigned short* bpL = sLb + ((size_t)((kh*4 + hi4)*144 + lo16))*8;
      #pragma unroll
      for (int mt = 0; mt < MT; ++mt) {
        short8 bl = *reinterpret_cast<const short8*>(bpL + mt*128);
        acc[mt] = __builtin_amdgcn_mfma_f32_16x16x32_bf16(whi, bl, acc[mt], 0, 0, 0);
      }
      __syncthreads();                 // H staged + W(step+1) landed; L free
      if (step < 7) {
        #pragma unroll
        for (int j = 0; j < 8; ++j) wv[j] = wvn[j];
      }
    }

    // ---- combine k-halves through LDS (smem reused as sAcc/sEs/sMx) ----
    if (kh == 1) {
      #pragma unroll
      for (int mt = 0; mt < MT; ++mt) sAcc[sub][mt][lane] = acc[mt];
    }
    __syncthreads();

    if (kh == 0) {
      // epilogue: D[m=c-local=(hi4*4+v)][n=row=lo16]; tgt from aminS
      #pragma unroll
      for (int mt = 0; mt < MT; ++mt) {
        const int row = r0 + mt*16 + lo16;
        int tgt = -1;
        if (row < nA) {
          const unsigned long long* ap = ws->aminS + (size_t)(row*NG + g)*QS;
          unsigned long long m = ap[0];
          #pragma unroll
          for (int s2 = 1; s2 < QS; ++s2) {
            unsigned long long v = ap[s2];
            if (v < m) m = v;
          }
          tgt = (int)(unsigned)(m & 0xFFFFFFFFull);
          if (blockIdx.x == 0 && wave == 0 && hi4 == 0)
            ws->targets[row*NG + g] = tgt;
        }
        f32x4 oth = sAcc[sub][mt][lane];
        float lv[4];
        #pragma unroll
        for (int v = 0; v < 4; ++v) lv[v] = (acc[mt][v] + oth[v]) + bv[v];
        #pragma unroll
        for (int v = 0; v < 4; ++v)
          if (tgt == cOut0 + v) ws->tLogit[row*NG + g] = lv[v];
        float es = expf(lv[0]) + expf(lv[1]) + expf(lv[2]) + expf(lv[3]);
        float mv = lv[0]; int mi = cOut0;
        if (lv[1] > mv) { mv = lv[1]; mi = cOut0+1; }
        if (lv[2] > mv) { mv = lv[2]; mi = cOut0+2; }
        if (lv[3] > mv) { mv = lv[3]; mi = cOut0+3; }
        #pragma unroll
        for (int off = 16; off <= 32; off <<= 1) {
          es += __shfl_xor(es, off);
          float ov = __shfl_xor(mv, off);
          int   oi = __shfl_xor(mi, off);
          if (ov > mv || (ov == mv && oi < mi)) { mv = ov; mi = oi; }
        }
        if (hi4 == 0) {
          sEs[sub][mt*16 + lo16] = es;
          unsigned key = __float_as_uint(mv);
          key = (key & 0x80000000u) ? ~key : (key | 0x80000000u);
          sMx[sub][mt*16 + lo16] = ((unsigned long long)key << 32)
                                 | (unsigned long long)(0xFFFFFFFFu - (unsigned)mi);
        }
      }
    }
    __syncthreads();
    if (tid < ROWCH) {
      float e = sEs[0][tid] + sEs[1][tid] + sEs[2][tid] + sEs[3][tid];
      unsigned long long m0 = sMx[0][tid], m1 = sMx[1][tid];
      unsigned long long m2 = sMx[2][tid], m3 = sMx[3][tid];
      unsigned long long ma = m0 > m1 ? m0 : m1;
      unsigned long long mb = m2 > m3 ? m2 : m3;
      unsigned long long mx = ma > mb ? ma : mb;
      int grow = r0 + tid;
      ws->part_se[g][grow][blockIdx.x] = e;
      ws->part_mx[g][grow][blockIdx.x] = mx;
    }
    __syncthreads();
  }
}

// ---- reduce 128 c-tile partials per (row,g): plain stores, no atomics ----
__global__ __launch_bounds__(256) void k_red_l(Ws* ws) {
  int nA = (int)ws->nA;
  int pair = blockIdx.x*4 + (threadIdx.x >> 6);
  int lane = threadIdx.x & 63;
  int row = pair >> 2, g = pair & 3;
  if (row >= nA) return;
  float e = ws->part_se[g][row][lane] + ws->part_se[g][row][lane + 64];
  unsigned long long a = ws->part_mx[g][row][lane];
  unsigned long long b = ws->part_mx[g][row][lane + 64];
  unsigned long long mx = a > b ? a : b;
  #pragma unroll
  for (int off = 32; off; off >>= 1) {
    e += __shfl_xor(e, off);
    unsigned long long o = __shfl_xor(mx, off);
    if (o > mx) mx = o;
  }
  if (lane == 0) {
    ws->sumExp[row*NG + g] = e;
    ws->amax[row*NG + g] = mx;
  }
}

// ======================= fallback fp32 path (round-1, proven) ==============
__global__ __launch_bounds__(256) void k_quant(
    const float* __restrict__ feats, const float* __restrict__ mean,
    const float* __restrict__ istd, const float* __restrict__ projw,
    const float* __restrict__ emb, Ws* ws) {
  if (blockIdx.x >= ws->nA) return;
  int ai = blockIdx.x;
  int p = ws->activeList[ai];
  int b = p >> 8, ts = p & (NTS-1);
  int tid = threadIdx.x;
  __shared__ float sN[SFD];
  __shared__ float sPart[4*64];
  __shared__ float sLat[NG*NE];
  __shared__ float sRedS[256];
  __shared__ int   sRedC[256];
  __shared__ float rS[4], rQ[4];
  __shared__ int   sTgt[NG];

  for (int j = tid; j < SFD; j += 256) {
    int k = j / NF, f = j - k*NF;
    sN[j] = (feats[((size_t)b*NT + ts*NSTRIDE + k)*NF + f] - mean[f]) * istd[f];
  }
  __syncthreads();
  float s = 0.f, q = 0.f;
  for (int j = tid; j < SFD; j += 256) { float x = sN[j]; s += x; q += x*x; }
  for (int o = 32; o; o >>= 1) { s += __shfl_down(s, o); q += __shfl_down(q, o); }
  if ((tid & 63) == 0) { rS[tid>>6] = s; rQ[tid>>6] = q; }
  __syncthreads();
  float mu  = (rS[0]+rS[1]+rS[2]+rS[3]) * (1.f/SFD);
  float var = (rQ[0]+rQ[1]+rQ[2]+rQ[3]) * (1.f/SFD) - mu*mu;
  float inv = rsqrtf(var + LNEPS);
  for (int j = tid; j < SFD; j += 256) sN[j] = (sN[j]-mu)*inv;
  __syncthreads();
  {
    int j = tid & 63, part = tid >> 6;
    float a = 0.f;
    int i0 = part*80;
    for (int i = i0; i < i0+80; ++i) a = fmaf(sN[i], projw[i*64 + j], a);
    sPart[part*64 + j] = a;
  }
  __syncthreads();
  if (tid < 64) sLat[tid] = sPart[tid] + sPart[64+tid] + sPart[128+tid] + sPart[192+tid];
  __syncthreads();

  for (int gg = 0; gg < NG; ++gg) {
    float lg[NE];
    #pragma unroll
    for (int e = 0; e < NE; ++e) lg[e] = sLat[gg*NE + e];
    float best = 3.4e38f; int bc = NC;
    for (int c = tid; c < NC; c += 256) {
      const float4* cb4 = reinterpret_cast<const float4*>(emb + ((size_t)c*NG + gg)*NE);
      float4 a0 = cb4[0], a1 = cb4[1], a2 = cb4[2], a3 = cb4[3];
      float dot = 0.f, n2 = 0.f;
      dot = fmaf(lg[0],  a0.x, dot); n2 = fmaf(a0.x, a0.x, n2);
      dot = fmaf(lg[1],  a0.y, dot); n2 = fmaf(a0.y, a0.y, n2);
      dot = fmaf(lg[2],  a0.z, dot); n2 = fmaf(a0.z, a0.z, n2);
      dot = fmaf(lg[3],  a0.w, dot); n2 = fmaf(a0.w, a0.w, n2);
      dot = fmaf(lg[4],  a1.x, dot); n2 = fmaf(a1.x, a1.x, n2);
      dot = fmaf(lg[5],  a1.y, dot); n2 = fmaf(a1.y, a1.y, n2);
      dot = fmaf(lg[6],  a1.z, dot); n2 = fmaf(a1.z, a1.z, n2);
      dot = fmaf(lg[7],  a1.w, dot); n2 = fmaf(a1.w, a1.w, n2);
      dot = fmaf(lg[8],  a2.x, dot); n2 = fmaf(a2.x, a2.x, n2);
      dot = fmaf(lg[9],  a2.y, dot); n2 = fmaf(a2.y, a2.y, n2);
      dot = fmaf(lg[10], a2.z, dot); n2 = fmaf(a2.z, a2.z, n2);
      dot = fmaf(lg[11], a2.w, dot); n2 = fmaf(a2.w, a2.w, n2);
      dot = fmaf(lg[12], a3.x, dot); n2 = fmaf(a3.x, a3.x, n2);
      dot = fmaf(lg[13], a3.y, dot); n2 = fmaf(a3.y, a3.y, n2);
      dot = fmaf(lg[14], a3.z, dot); n2 = fmaf(a3.z, a3.z, n2);
      dot = fmaf(lg[15], a3.w, dot); n2 = fmaf(a3.w, a3.w, n2);
      float sc = n2 - 2.f*dot;
      if (sc < best) { best = sc; bc = c; }
    }
    sRedS[tid] = best; sRedC[tid] = bc;
    __syncthreads();
    for (int off = 128; off; off >>= 1) {
      if (tid < off) {
        float os = sRedS[tid+off]; int oc = sRedC[tid+off];
        if (os < sRedS[tid] || (os == sRedS[tid] && oc < sRedC[tid])) {
          sRedS[tid] = os; sRedC[tid] = oc;
        }
      }
      __syncthreads();
    }
    if (tid == 0) sTgt[gg] = sRedC[0];
    __syncthreads();
  }
  if (tid < NG) ws->targets[ai*NG + tid] = sTgt[tid];
}

__global__ __launch_bounds__(256) void k_logits(
    const float* __restrict__ W, const float* __restrict__ bias,
    const float* __restrict__ enc, Ws* ws) {
  const int nA = (int)ws->nA;
  if (nA == 0) return;
  const int nCh = (nA + PCH - 1) / PCH;
  const int g = blockIdx.y;
  const int cbase = blockIdx.x * TCC + threadIdx.x * CPT;
  const float* __restrict__ Wg = W + (size_t)g*ND*NC;
  const float b0 = bias[g*NC + cbase + 0];
  const float b1 = bias[g*NC + cbase + 1];
  const float b2 = bias[g*NC + cbase + 2];
  const float b3 = bias[g*NC + cbase + 3];
  __shared__ float4 sEnc[PCH][ND/4];
  __shared__ int sP[PCH];

  for (int ch = blockIdx.z; ch < nCh; ch += PB) {
    if (threadIdx.x < PCH) {
      int ai = ch*PCH + threadIdx.x;
      sP[threadIdx.x] = (ai < nA) ? ws->activeList[ai] : -1;
    }
    __syncthreads();
    for (int i = threadIdx.x; i < PCH*(ND/4); i += 256) {
      int qq = i >> 7, r = i & 127;
      int p = sP[qq];
      sEnc[qq][r] = (p >= 0) ? reinterpret_cast<const float4*>(enc)[p*(ND/4) + r]
                             : make_float4(0.f, 0.f, 0.f, 0.f);
    }
    __syncthreads();

    float acc[PCH][CPT];
    #pragma unroll
    for (int qq = 0; qq < PCH; ++qq)
      #pragma unroll
      for (int j = 0; j < CPT; ++j) acc[qq][j] = 0.f;
    for (int d = 0; d < ND; d += 4) {
      const float* wp = Wg + (size_t)d*NC + cbase;
      float4 w0 = *reinterpret_cast<const float4*>(wp);
      float4 w1 = *reinterpret_cast<const float4*>(wp + NC);
      float4 w2 = *reinterpret_cast<const float4*>(wp + 2*NC);
      float4 w3 = *reinterpret_cast<const float4*>(wp + 3*NC);
      int dq = d >> 2;
      #pragma unroll
      for (int qq = 0; qq < PCH; ++qq) {
        float4 e = sEnc[qq][dq];
        acc[qq][0] = fmaf(e.x, w0.x, acc[qq][0]);
        acc[qq][1] = fmaf(e.x, w0.y, acc[qq][1]);
        acc[qq][2] = fmaf(e.x, w0.z, acc[qq][2]);
        acc[qq][3] = fmaf(e.x, w0.w, acc[qq][3]);
        acc[qq][0] = fmaf(e.y, w1.x, acc[qq][0]);
        acc[qq][1] = fmaf(e.y, w1.y, acc[qq][1]);
        acc[qq][2] = fmaf(e.y, w1.z, acc[qq][2]);
        acc[qq][3] = fmaf(e.y, w1.w, acc[qq][3]);
        acc[qq][0] = fmaf(e.z, w2.x, acc[qq][0]);
        acc[qq][1] = fmaf(e.z, w2.y, acc[qq][1]);
        acc[qq][2] = fmaf(e.z, w2.z, acc[qq][2]);
        acc[qq][3] = fmaf(e.z, w2.w, acc[qq][3]);
        acc[qq][0] = fmaf(e.w, w3.x, acc[qq][0]);
        acc[qq][1] = fmaf(e.w, w3.y, acc[qq][1]);
        acc[qq][2] = fmaf(e.w, w3.z, acc[qq][2]);
        acc[qq][3] = fmaf(e.w, w3.w, acc[qq][3]);
      }
    }

    #pragma unroll
    for (int qq = 0; qq < PCH; ++qq) {
      int ai = ch*PCH + qq;
      if (ai < nA) {
        float l0 = acc[qq][0] + b0;
        float l1 = acc[qq][1] + b1;
        float l2 = acc[qq][2] + b2;
        float l3 = acc[qq][3] + b3;
        int tgt = ws->targets[ai*NG + g];
        if ((unsigned)(tgt - cbase) < (unsigned)CPT) {
          float tv = (tgt == cbase) ? l0 : (tgt == cbase+1) ? l1
                   : (tgt == cbase+2) ? l2 : l3;
          ws->tLogit[ai*NG + g] = tv;
        }
        float es = expf(l0) + expf(l1) + expf(l2) + expf(l3);
        float mv = l0; int mi = cbase;
        if (l1 > mv) { mv = l1; mi = cbase+1; }
        if (l2 > mv) { mv = l2; mi = cbase+2; }
        if (l3 > mv) { mv = l3; mi = cbase+3; }
        for (int o = 32; o; o >>= 1) {
          es += __shfl_down(es, o);
          float ov = __shfl_down(mv, o);
          int   oi = __shfl_down(mi, o);
          if (ov > mv || (ov == mv && oi < mi)) { mv = ov; mi = oi; }
        }
        if ((threadIdx.x & 63) == 0) {
          atomicAdd(&ws->sumExp[ai*NG + g], es);
          unsigned key = __float_as_uint(mv);
          key = (key & 0x80000000u) ? ~key : (key | 0x80000000u);
          unsigned long long pk =
              ((unsigned long long)key << 32) |
              (unsigned long long)(0xFFFFFFFFu - (unsigned)mi);
          atomicMax(&ws->amax[ai*NG + g], pk);
        }
      }
    }
    __syncthreads();
  }
}
// ======================= end fallback =======================================

// ---- final scalar assembly (uniq bitmap in LDS; pen from penPart) ----
__global__ __launch_bounds__(256) void k_final(Ws* ws, float* __restrict__ out) {
  int tid = threadIdx.x;
  int nA = (int)ws->nA;
  __shared__ unsigned sbm[NC/32];   // 256 words == blockDim
  sbm[tid] = 0u;
  __syncthreads();

  float sumPer = 0.f, sumCorr = 0.f;
  for (int i = tid; i < nA*NG; i += 256) {
    int tgt = ws->targets[i];
    sumPer += logf(ws->sumExp[i]) - ws->tLogit[i];
    unsigned long long pk = ws->amax[i];
    int mi = (int)(0xFFFFFFFFu - (unsigned)(pk & 0xFFFFFFFFull));
    if (mi == tgt) sumCorr += 1.f;
    atomicOr(&sbm[tgt >> 5], 1u << (tgt & 31));
  }
  __syncthreads();
  unsigned w = sbm[tid];
  if (tid == 0 && nA < NP) w |= 1u;   // masked positions contribute code 0
  int uniq = __popc(w);
  float pen1 = ws->penPart[tid];

  __shared__ float rs[4], rc[4], rp[4]; __shared__ int ru[4];
  float s1 = sumPer, s2 = sumCorr, s4 = pen1; int s3 = uniq;
  for (int o = 32; o; o >>= 1) {
    s1 += __shfl_down(s1, o);
    s2 += __shfl_down(s2, o);
    s3 += __shfl_down(s3, o);
    s4 += __shfl_down(s4, o);
  }
  if ((tid & 63) == 0) { rs[tid>>6] = s1; rc[tid>>6] = s2; ru[tid>>6] = s3; rp[tid>>6] = s4; }
  __syncthreads();
  if (tid == 0) {
    float sp = rs[0]+rs[1]+rs[2]+rs[3];
    float sc = rc[0]+rc[1]+rc[2]+rc[3];
    int   un = ru[0]+ru[1]+ru[2]+ru[3];
    float ps = rp[0]+rp[1]+rp[2]+rp[3];
    float pen   = ps / (float)(NB*NT*NF);
    float denom = (float)nA + 1e-5f;
    float nc    = (float)(nA * NG);
    out[0] = sp / (denom * (float)NG) + FREG * pen;
    out[1] = sc / nc;
    out[2] = pen;
    out[3] = nc;
    out[4] = (float)un;
  }
}

extern "C" void kernel_launch(void* const* d_in, const int* in_sizes, int n_in,
                              void* d_out, int out_size, void* d_ws, size_t ws_size,
                              hipStream_t stream) {
  const float* feats = (const float*)d_in[0];
  const int*   lens  = (const int*)d_in[1];
  const unsigned char* masks = (const unsigned char*)d_in[2];
  const float* mean  = (const float*)d_in[4];
  const float* istd  = (const float*)d_in[5];
  const float* projw = (const float*)d_in[6];
  const float* emb   = (const float*)d_in[7];
  const float* W     = (const float*)d_in[8];
  const float* bias  = (const float*)d_in[9];
  const float* enc   = (const float*)d_in[10];
  Ws* ws = (Ws*)d_ws;
  float* out = (float*)d_out;

  bool big = ws_size >= sizeof(Ws);
  if (big) {
    k_prologue<<<256, 256, 0, stream>>>(feats, mean, istd, masks, lens, 1, ws);
    k_latprep<<<ROWS_MAX, 256, 0, stream>>>(feats, mean, istd, projw, enc, ws);
    k_qdist<<<dim3(NC/64, QY), 256, 0, stream>>>(emb, ws);
    k_logits_mfma<<<dim3(CT, NG), 512, 0, stream>>>(W, bias, ws);
    k_red_l<<<NP, 256, 0, stream>>>(ws);
  } else {
    size_t zr = offsetof(Ws, aminS);
    hipMemsetAsync(d_ws, 0, ws_size < zr ? ws_size : zr, stream);
    k_prologue<<<256, 256, 0, stream>>>(feats, mean, istd, masks, lens, 0, ws);
    k_quant<<<NP, 256, 0, stream>>>(feats, mean, istd, projw, emb, ws);
    k_logits<<<dim3(NC/TCC, NG, PB), 256, 0, stream>>>(W, bias, enc, ws);
  }
  k_final<<<1, 256, 0, stream>>>(ws, out);
}